// Round 6
// baseline (187.129 us; speedup 1.0000x reference)
//
#include <hip/hip_runtime.h>

// CustomRNN: B=2048, T=512, I=1, H=64. One wave per batch.
// Evolution:
//  R0: full-h LDS broadcast (16 ds_read_b128/step), 172us (LDS-BW).
//  R2: 4-way K-split + shfl_xor butterfly, 158us (chain: 2 bpermute hops).
//  R4: readlane broadcast, 228us (issue explosion). Reverted.
//  R5: quad-local butterfly via DPP quad_perm, 134us (rocprof).
//      VALUBusy 70% @ 628cy/step/SIMD: issue ~220cy/wave (32 pk_fma_f32 =
//      128cy: packed f32 occupies the SIMD-32 datapath 4cy/instr) + ~190cy
//      un-hidden chain (ds_read ~120, write->read turnaround ~150).
//  R6 (this): f16 dot path. W_hh cached as packed f16 (RTN, init-only);
//      h stored in LDS as f16. v_dot2_f32_f16 = 2 f16 MAC/lane with F32
//      ACCUMULATOR at full rate (2cy/wave64 instr): dot issue 128->64cy,
//      LDS reads 4->2 ds_read_b128, horizontal v2f adds gone. Butterfly /
//      bias-after-reduction / tanh / epilogue identical to passing R5.
//      Precision: W quant 2^-11 rel, h quant 4.9e-4/step, accum f32;
//      expected absmax ~1e-3 vs 7.89e-3 threshold.
// Quad-local mapping (p = lane&3, rows l, l^1, l^2, l^3; verified in R5):
//   u0 = sA + qperm_xor1(sB); u1 = sC + qperm_xor1(sD);
//   z  = u0 + qperm_xor2(u1)  -> full 64-dot of row l lands on lane l.

typedef float v2f __attribute__((ext_vector_type(2)));
typedef float v4f __attribute__((ext_vector_type(4)));
typedef _Float16 f16;
typedef _Float16 f16x2 __attribute__((ext_vector_type(2)));
typedef _Float16 f16x8 __attribute__((ext_vector_type(8)));

#define WPB 4  // waves (== batches) per block

#define DPP_XOR1 0xB1  // quad_perm:[1,0,3,2]
#define DPP_XOR2 0x4E  // quad_perm:[2,3,0,1]

#if __has_builtin(__builtin_amdgcn_mov_dpp)
template <int CTRL>
__device__ __forceinline__ float qperm(float x) {
    return __int_as_float(__builtin_amdgcn_mov_dpp(
        __float_as_int(x), CTRL, 0xF, 0xF, true));
}
#else
template <int CTRL>
__device__ __forceinline__ float qperm(float x) {
    // identical lane mapping: xor on lane-id bits 0-1
    return __shfl_xor(x, (CTRL == DPP_XOR1) ? 1 : 2, 64);
}
#endif

__device__ __forceinline__ float fdot2(f16x2 a, f16x2 b, float c) {
#if __has_builtin(__builtin_amdgcn_fdot2)
    return __builtin_amdgcn_fdot2(a, b, c, false);
#else
    return __builtin_fmaf((float)a.x, (float)b.x,
           __builtin_fmaf((float)a.y, (float)b.y, c));
#endif
}

__global__ __launch_bounds__(WPB * 64)
__attribute__((amdgpu_waves_per_eu(2, 2)))  // pin VGPR budget: weight cache
void rnn_fused(
    const float* __restrict__ x,      // [B, T, 1]
    const float* __restrict__ W_ih,   // [64, 1]
    const float* __restrict__ W_hh,   // [64, 64]
    const float* __restrict__ b_ih,   // [64]
    const float* __restrict__ b_hh,   // [64]
    const float* __restrict__ fc_w,   // [1, 64]
    const float* __restrict__ fc_b,   // [1]
    float* __restrict__ out,          // [B, 1]
    int B, int T)
{
    const int lane  = threadIdx.x & 63;
    const int wv    = threadIdx.x >> 6;
    const int batch = blockIdx.x * WPB + wv;
    if (batch >= B) return;  // no block-wide sync anywhere; early exit safe

    const int p = lane & 3;    // k-segment: k in [16p, 16p+16)

    __shared__ __align__(16) f16   hsh[WPB][64];  // h state, packed f16
    __shared__ __align__(16) float xs[WPB][64];

    // Rows accumulated by this lane (quad-local window): l, l^1, l^2, l^3.
    const int rA = lane;
    const int rB = lane ^ 1;
    const int rC = lane ^ 2;
    const int rD = lane ^ 3;

    // 4 rows x 16 weights as packed f16 pairs: 8 f16x2 per row = 32 VGPRs.
    f16x2 wA[8], wB[8], wC[8], wD[8];
    {
        const v4f* pA = (const v4f*)(W_hh + rA * 64 + 16 * p);
        const v4f* pB = (const v4f*)(W_hh + rB * 64 + 16 * p);
        const v4f* pC = (const v4f*)(W_hh + rC * 64 + 16 * p);
        const v4f* pD = (const v4f*)(W_hh + rD * 64 + 16 * p);
#pragma unroll
        for (int c = 0; c < 4; ++c) {
            const v4f tA = pA[c], tB = pB[c], tC = pC[c], tD = pD[c];
            wA[2*c]   = (f16x2){(f16)tA.x, (f16)tA.y};
            wA[2*c+1] = (f16x2){(f16)tA.z, (f16)tA.w};
            wB[2*c]   = (f16x2){(f16)tB.x, (f16)tB.y};
            wB[2*c+1] = (f16x2){(f16)tB.z, (f16)tB.w};
            wC[2*c]   = (f16x2){(f16)tC.x, (f16)tC.y};
            wC[2*c+1] = (f16x2){(f16)tC.z, (f16)tC.w};
            wD[2*c]   = (f16x2){(f16)tD.x, (f16)tD.y};
            wD[2*c+1] = (f16x2){(f16)tD.z, (f16)tD.w};
        }
    }
    const float wih_j  = W_ih[lane];            // final a[j] lands on lane j
    const float bias_j = b_ih[lane] + b_hh[lane];

    const float* xb = x + (size_t)batch * T;

    hsh[wv][lane] = (f16)0.0f;
    __builtin_amdgcn_wave_barrier();

    float hcur = 0.0f;  // lane l holds h[l] in f32; LDS mirror is f16

    auto step = [&](float xv) {
        // Read this lane's 16-f16 h segment: 2 ds_read_b128.
        // Segment bases for p=0..3 hit disjoint bank groups; 16-lane
        // same-address groups broadcast. Conflict-free.
        const f16x8* hseg = (const f16x8*)(&hsh[wv][p * 16]);
        const f16x8 hL = hseg[0], hH = hseg[1];
        f16x2 hp[8];
        hp[0] = __builtin_shufflevector(hL, hL, 0, 1);
        hp[1] = __builtin_shufflevector(hL, hL, 2, 3);
        hp[2] = __builtin_shufflevector(hL, hL, 4, 5);
        hp[3] = __builtin_shufflevector(hL, hL, 6, 7);
        hp[4] = __builtin_shufflevector(hH, hH, 0, 1);
        hp[5] = __builtin_shufflevector(hH, hH, 2, 3);
        hp[6] = __builtin_shufflevector(hH, hH, 4, 5);
        hp[7] = __builtin_shufflevector(hH, hH, 6, 7);

        // Per row: two 4-deep dot2 chains (f32 accumulate), then combine.
        float sA0 = 0.f, sB0 = 0.f, sC0 = 0.f, sD0 = 0.f;
        float sA1 = 0.f, sB1 = 0.f, sC1 = 0.f, sD1 = 0.f;
#pragma unroll
        for (int j = 0; j < 4; ++j) {
            sA0 = fdot2(hp[j], wA[j], sA0);
            sB0 = fdot2(hp[j], wB[j], sB0);
            sC0 = fdot2(hp[j], wC[j], sC0);
            sD0 = fdot2(hp[j], wD[j], sD0);
        }
#pragma unroll
        for (int j = 4; j < 8; ++j) {
            sA1 = fdot2(hp[j], wA[j], sA1);
            sB1 = fdot2(hp[j], wB[j], sB1);
            sC1 = fdot2(hp[j], wC[j], sC1);
            sD1 = fdot2(hp[j], wD[j], sD1);
        }
        const float sA = sA0 + sA1, sB = sB0 + sB1;
        const float sC = sC0 + sC1, sD = sD0 + sD1;

        // Quad-local reduce-scatter, all VALU (verified in R5):
        const float u0 = sA + qperm<DPP_XOR1>(sB);
        const float u1 = sC + qperm<DPP_XOR1>(sD);
        const float z  = u0 + qperm<DPP_XOR2>(u1);
        // Per-row bias/x term strictly AFTER reduction.
        const float a  = z + __builtin_fmaf(xv, wih_j, bias_j);

        // tanh(a) = sign(a) * (1 - e) / (1 + e),  e = exp(-2|a|)
        const float ax = __builtin_fabsf(a);
        const float e  = __builtin_amdgcn_exp2f(ax * -2.885390082f); // exp(-2ax)
        const float rc = __builtin_amdgcn_rcpf(1.0f + e);
        hcur = __builtin_copysignf((1.0f - e) * rc, a);

        __builtin_amdgcn_wave_barrier();   // all reads of this step done
        hsh[wv][lane] = (f16)hcur;         // ds_write_b16 (2-lane/bank: free)
        __builtin_amdgcn_wave_barrier();   // write ordered before next reads
    };

    for (int t0 = 0; t0 < T; t0 += 64) {
        const int rem = T - t0;
        // Stage up to 64 input scalars for this batch (coalesced 256B load).
        xs[wv][lane] = (lane < rem) ? xb[t0 + lane] : 0.0f;
        __builtin_amdgcn_wave_barrier();

        if (rem >= 64) {
            const v4f* xs4 = (const v4f*)(&xs[wv][0]);
            for (int t4 = 0; t4 < 16; ++t4) {
                const v4f xq = xs4[t4];  // one broadcast b128 per 4 steps
                step(xq.x);
                step(xq.y);
                step(xq.z);
                step(xq.w);
            }
        } else {
            for (int tt = 0; tt < rem; ++tt) step(xs[wv][tt]);
        }
    }

    // fc: out[b] = sum_j h[j] * fc_w[j] + fc_b   (lane j holds h[j], f32)
    float v = hcur * fc_w[lane];
#pragma unroll
    for (int off = 32; off > 0; off >>= 1)
        v += __shfl_xor(v, off, 64);
    if (lane == 0) out[batch] = v + fc_b[0];
}

extern "C" void kernel_launch(void* const* d_in, const int* in_sizes, int n_in,
                              void* d_out, int out_size, void* d_ws, size_t ws_size,
                              hipStream_t stream) {
    const float* x    = (const float*)d_in[0];
    const float* W_ih = (const float*)d_in[1];
    const float* W_hh = (const float*)d_in[2];
    const float* b_ih = (const float*)d_in[3];
    const float* b_hh = (const float*)d_in[4];
    const float* fc_w = (const float*)d_in[5];
    const float* fc_b = (const float*)d_in[6];
    float* out = (float*)d_out;

    const int B = out_size;          // output is [B, 1]
    const int T = in_sizes[0] / B;   // I == 1, so x has B*T elements

    const int blocks = (B + WPB - 1) / WPB;
    rnn_fused<<<blocks, WPB * 64, 0, stream>>>(x, W_ih, W_hh, b_ih, b_hh,
                                               fc_w, fc_b, out, B, T);
}